// Round 7
// baseline (449.817 us; speedup 1.0000x reference)
//
#include <hip/hip_runtime.h>

#define N_NODES  50000
#define N_EDGES  600000
#define DIM      128
#define N_GRAPHS 128
#define N_CLASSES 10
#define NB_SCAN  196          // ceil(50000/256)
#define ZWORDS   1700000      // zero region: deg+cnt+epk (words)
#define NZB4     1661         // ceil(ZWORDS/4/256)
#define NPB      16           // psum zero blocks: 16384 words /4 /256

// NOTE: harness delivers ALL integer inputs as int32 (const int*).

typedef __bf16 bf16x8 __attribute__((ext_vector_type(8)));
typedef float  f32x4  __attribute__((ext_vector_type(4)));

__device__ inline unsigned short f2bf(float f) {      // RNE float->bf16
  union { float f; unsigned int i; } u; u.f = f;
  unsigned int r = u.i + 0x7fff + ((u.i >> 16) & 1);
  return (unsigned short)(r >> 16);
}
__device__ inline float bf2f(unsigned short s) {
  union { unsigned int i; float f; } u; u.i = ((unsigned int)s) << 16;
  return u.f;
}
__device__ inline bf16x8 pack8(float4 lo, float4 hi) {
  union { bf16x8 v; unsigned short s[8]; } u;
  u.s[0] = f2bf(lo.x); u.s[1] = f2bf(lo.y); u.s[2] = f2bf(lo.z); u.s[3] = f2bf(lo.w);
  u.s[4] = f2bf(hi.x); u.s[5] = f2bf(hi.y); u.s[6] = f2bf(hi.z); u.s[7] = f2bf(hi.w);
  return u.v;
}
__device__ inline bf16x8 zero8() {
  union { bf16x8 v; unsigned short s[8]; } u;
#pragma unroll
  for (int j = 0; j < 8; ++j) u.s[j] = 0;
  return u.v;
}

// ---------------- prep: zero CSR scratch + psum (float4) + pack weights -------

__global__ __launch_bounds__(256) void k_prep(float4* __restrict__ z4,
                                              float4* __restrict__ pz,
                                              const float* __restrict__ W1,
                                              const float* __restrict__ R1,
                                              const float* __restrict__ Wc,
                                              const float* __restrict__ Rc,
                                              unsigned short* __restrict__ pk) {
  if (blockIdx.x < NZB4) {
    int i = blockIdx.x * 256 + threadIdx.x;
    if (i < ZWORDS / 4) z4[i] = make_float4(0.f, 0.f, 0.f, 0.f);
    return;
  }
  if (blockIdx.x < NZB4 + NPB) {        // zero psum: 16*256 = 4096 float4 exact
    int i = (blockIdx.x - NZB4) * 256 + threadIdx.x;
    pz[i] = make_float4(0.f, 0.f, 0.f, 0.f);
    return;
  }
  int pb = blockIdx.x - NZB4 - NPB;     // 0..63
  int mm = pb >> 3, sub = pb & 7;
  const float* src = (mm == 0) ? W1
                   : (mm < 4)  ? Wc + (size_t)(mm - 1) * DIM * DIM
                   : (mm == 4) ? R1
                               : Rc + (size_t)(mm - 5) * DIM * DIM;
  int idx = sub * 256 + threadIdx.x;    // 0..2047 fragment-lane slots
  int lane = idx & 63;
  int kc   = (idx >> 6) & 3;
  int nt   = idx >> 8;
  int col  = nt * 16 + (lane & 15);
  int k0   = kc * 32 + (lane >> 4) * 8;
  unsigned short* dst = pk + (size_t)mm * 16384 + (size_t)idx * 8;
  ushort4 u;
  u.x = f2bf(src[(k0 + 0) * DIM + col]);
  u.y = f2bf(src[(k0 + 1) * DIM + col]);
  u.z = f2bf(src[(k0 + 2) * DIM + col]);
  u.w = f2bf(src[(k0 + 3) * DIM + col]);
  *(ushort4*)&dst[0] = u;
  u.x = f2bf(src[(k0 + 4) * DIM + col]);
  u.y = f2bf(src[(k0 + 5) * DIM + col]);
  u.z = f2bf(src[(k0 + 6) * DIM + col]);
  u.w = f2bf(src[(k0 + 7) * DIM + col]);
  *(ushort4*)&dst[4] = u;
}

// ---------------- CSR build (padded x8; packed int2{src, w_bits}) -------------
// Pad slots stay {0, 0.0f}: gathers hit row 0 (hot), weight 0 -> contribute 0.

__global__ __launch_bounds__(256) void k_deg(const int* __restrict__ ei,
                                             int* __restrict__ deg) {
  int e = blockIdx.x * 256 + threadIdx.x;
  if (e < N_EDGES) atomicAdd(&deg[ei[N_EDGES + e]], 1);
}

__global__ __launch_bounds__(256) void k_dinvsum(const int* __restrict__ deg,
                                                 float* __restrict__ dinv,
                                                 int* __restrict__ bsum) {
  int i = blockIdx.x * 256 + threadIdx.x;
  int t = threadIdx.x;
  int d = (i < N_NODES) ? deg[i] : 0;
  if (i < N_NODES) dinv[i] = (d > 0) ? rsqrtf((float)d) : 0.f;
  int dp = (d + 7) & ~7;
  __shared__ int tmp[256];
  tmp[t] = dp;
  __syncthreads();
  for (int off = 128; off > 0; off >>= 1) {
    if (t < off) tmp[t] += tmp[t + off];
    __syncthreads();
  }
  if (t == 0) bsum[blockIdx.x] = tmp[0];
}

__global__ __launch_bounds__(256) void k_bscan(const int* __restrict__ bsum,
                                               int* __restrict__ boff,
                                               int* __restrict__ rowp) {
  int t = threadIdx.x;
  int v = (t < NB_SCAN) ? bsum[t] : 0;
  __shared__ int tmp[256];
  tmp[t] = v;
  __syncthreads();
  for (int off = 1; off < 256; off <<= 1) {
    int add = (t >= off) ? tmp[t - off] : 0;
    __syncthreads();
    tmp[t] += add;
    __syncthreads();
  }
  boff[t] = tmp[t] - v;          // exclusive
  if (t == 255) rowp[N_NODES] = tmp[255];   // total padded edge count
}

__global__ __launch_bounds__(256) void k_rowp(const int* __restrict__ deg,
                                              const int* __restrict__ boff,
                                              int* __restrict__ rowp) {
  int i = blockIdx.x * 256 + threadIdx.x;
  int t = threadIdx.x;
  int dp = (i < N_NODES) ? ((deg[i] + 7) & ~7) : 0;
  __shared__ int tmp[256];
  tmp[t] = dp;
  __syncthreads();
  for (int off = 1; off < 256; off <<= 1) {
    int add = (t >= off) ? tmp[t - off] : 0;
    __syncthreads();
    tmp[t] += add;
    __syncthreads();
  }
  if (i < N_NODES) rowp[i] = boff[blockIdx.x] + tmp[t] - dp;  // exclusive
}

__global__ __launch_bounds__(256) void k_fill(const int* __restrict__ ei,
                                              const int* __restrict__ rowp,
                                              int* __restrict__ cnt,
                                              const float* __restrict__ dinv,
                                              int2* __restrict__ epk) {
  int e = blockIdx.x * 256 + threadIdx.x;
  if (e < N_EDGES) {
    int s = ei[e];
    int d = ei[N_EDGES + e];
    int p = rowp[d] + atomicAdd(&cnt[d], 1);
    epk[p] = make_int2(s, __float_as_int(dinv[s] * dinv[d]));  // one 8B store
  }
}

// ---------------- per-row edge sort by source (R7) ----------------------------
// Mechanism: all resident gather waves then walk ASCENDING source IDs roughly
// in lockstep -> instantaneous read frontier is a ~2-4MB band -> fits per-XCD
// L2 -> converts L3-random line service (the measured ~5TB/s ceiling) into L2
// hits. One thread per row; insertion sort of the ~12 real edges, in-place on
// epk (rows are L2-hot right after k_fill). Pads (src 0, w 0) stay at the tail
// -- correctness is order-independent, sorting is purely a locality opt.

__global__ __launch_bounds__(256) void k_rsort(const int* __restrict__ rowp,
                                               const int* __restrict__ deg,
                                               int2* __restrict__ epk) {
  int n = blockIdx.x * 256 + threadIdx.x;
  if (n >= N_NODES) return;
  int e0 = rowp[n];
  int d  = deg[n];
  for (int i = 1; i < d; ++i) {
    int2 key = epk[e0 + i];
    int j = i - 1;
    while (j >= 0) {
      int2 v = epk[e0 + j];
      if (v.x <= key.x) break;
      epk[e0 + j + 1] = v;
      --j;
    }
    epk[e0 + j + 1] = key;
  }
}

// ---------------- x -> bf16 cast (once): xb = bf16(x) -------------------------
// COMMUTATION (R6): agg is row-linear, so agg(g@W) == agg(g)@W. We gather the
// ACTIVATION g itself and fold both matmuls + skip into one GEMM:
//   g_{l} = relu(agg(g_{l-1})@W_l + g_{l-1}@R_l + b_l)

__global__ __launch_bounds__(256) void k_xcast(const float* __restrict__ xf,
                                               unsigned short* __restrict__ xb) {
  int i = blockIdx.x * 256 + threadIdx.x;     // 800,000 chunks of 8, exact grid
  float4 lo = *(const float4*)&xf[i * 8];
  float4 hi = *(const float4*)&xf[i * 8 + 4];
  bf16x8 v = pack8(lo, hi);
  *(bf16x8*)&xb[i * 8] = v;
}

// ---------------- standalone gather: a = agg(gin)  (no skip, no relu) ---------
// R7: MONOTONE single-direction walk, 8 edges/iter (pad-8 guarantees multiple
// of 8). Dual-chain's both-ends walk would defeat the sorted frontier; R3
// proved chain topology itself is perf-neutral, so this keeps 8 gathers in
// flight while preserving ascending-source order.

__global__ __launch_bounds__(256) void k_gath(const unsigned short* __restrict__ hin,
                                              const int* __restrict__ rowp,
                                              const int2* __restrict__ epk,
                                              unsigned short* __restrict__ aout) {
  int n = blockIdx.x * 8 + (threadIdx.x >> 5);
  if (n >= N_NODES) return;
  int l4 = (threadIdx.x & 31) * 4;
  int e0 = rowp[n], e1 = rowp[n + 1];
  float4 accA = make_float4(0.f, 0.f, 0.f, 0.f);
  float4 accB = make_float4(0.f, 0.f, 0.f, 0.f);
  for (int e = e0; e < e1; e += 8) {
    int4 p0 = *(const int4*)&epk[e];
    int4 p1 = *(const int4*)&epk[e + 2];
    int4 p2 = *(const int4*)&epk[e + 4];
    int4 p3 = *(const int4*)&epk[e + 6];
    ushort4 u0 = *(const ushort4*)&hin[p0.x * DIM + l4];
    ushort4 u1 = *(const ushort4*)&hin[p0.z * DIM + l4];
    ushort4 u2 = *(const ushort4*)&hin[p1.x * DIM + l4];
    ushort4 u3 = *(const ushort4*)&hin[p1.z * DIM + l4];
    ushort4 u4 = *(const ushort4*)&hin[p2.x * DIM + l4];
    ushort4 u5 = *(const ushort4*)&hin[p2.z * DIM + l4];
    ushort4 u6 = *(const ushort4*)&hin[p3.x * DIM + l4];
    ushort4 u7 = *(const ushort4*)&hin[p3.z * DIM + l4];
    float w0 = __int_as_float(p0.y), w1 = __int_as_float(p0.w);
    float w2 = __int_as_float(p1.y), w3 = __int_as_float(p1.w);
    float w4 = __int_as_float(p2.y), w5 = __int_as_float(p2.w);
    float w6 = __int_as_float(p3.y), w7 = __int_as_float(p3.w);
    accA.x = fmaf(w0, bf2f(u0.x), fmaf(w1, bf2f(u1.x), fmaf(w2, bf2f(u2.x), fmaf(w3, bf2f(u3.x), accA.x))));
    accA.y = fmaf(w0, bf2f(u0.y), fmaf(w1, bf2f(u1.y), fmaf(w2, bf2f(u2.y), fmaf(w3, bf2f(u3.y), accA.y))));
    accA.z = fmaf(w0, bf2f(u0.z), fmaf(w1, bf2f(u1.z), fmaf(w2, bf2f(u2.z), fmaf(w3, bf2f(u3.z), accA.z))));
    accA.w = fmaf(w0, bf2f(u0.w), fmaf(w1, bf2f(u1.w), fmaf(w2, bf2f(u2.w), fmaf(w3, bf2f(u3.w), accA.w))));
    accB.x = fmaf(w4, bf2f(u4.x), fmaf(w5, bf2f(u5.x), fmaf(w6, bf2f(u6.x), fmaf(w7, bf2f(u7.x), accB.x))));
    accB.y = fmaf(w4, bf2f(u4.y), fmaf(w5, bf2f(u5.y), fmaf(w6, bf2f(u6.y), fmaf(w7, bf2f(u7.y), accB.y))));
    accB.z = fmaf(w4, bf2f(u4.z), fmaf(w5, bf2f(u5.z), fmaf(w6, bf2f(u6.z), fmaf(w7, bf2f(u7.z), accB.z))));
    accB.w = fmaf(w4, bf2f(u4.w), fmaf(w5, bf2f(u5.w), fmaf(w6, bf2f(u6.w), fmaf(w7, bf2f(u7.w), accB.w))));
  }
  ushort4 o;
  o.x = f2bf(accA.x + accB.x);
  o.y = f2bf(accA.y + accB.y);
  o.z = f2bf(accA.z + accB.z);
  o.w = f2bf(accA.w + accB.w);
  *(ushort4*)&aout[n * DIM + l4] = o;
}

// ---------------- dual-A MFMA GEMM: o = relu(a@W + g@R + b) -------------------
// Same HW-verified fragment layout as all previous GEMMs. Non-LAST: bf16 g_l
// (scalar epilogue, R5-proven). LAST: fp32 dlast + FUSED mean-pool (R5-proven
// segment-reduce idiom, extended to the block's 64 rows).

template<bool LAST>
__global__ __launch_bounds__(256) void k_gemmc(const unsigned short* __restrict__ aA,
                                               const unsigned short* __restrict__ gA,
                                               const unsigned short* __restrict__ pkW,
                                               const unsigned short* __restrict__ pkR,
                                               const float* __restrict__ bv,
                                               unsigned short* __restrict__ gout,
                                               float* __restrict__ dlast,
                                               const int* __restrict__ batch,
                                               float* __restrict__ psum) {
  const int tid  = threadIdx.x;
  const int wave = tid >> 6, lane = tid & 63;
  const int m = lane & 15, q = lane >> 4;
  const int rbase0 = blockIdx.x * 64;
  const int rbase  = rbase0 + wave * 16;
  const int arow   = rbase + m;
  const bool aok   = arow < N_NODES;

  bf16x8 a[4], g[4];
#pragma unroll
  for (int kc = 0; kc < 4; ++kc) {
    a[kc] = aok ? *(const bf16x8*)&aA[arow * DIM + kc * 32 + q * 8] : zero8();
    g[kc] = aok ? *(const bf16x8*)&gA[arow * DIM + kc * 32 + q * 8] : zero8();
  }

  f32x4 acc[16];
#pragma unroll
  for (int t = 0; t < 16; ++t) acc[t] = (f32x4){0.f, 0.f, 0.f, 0.f};

#pragma unroll
  for (int nt = 0; nt < 8; ++nt) {
    const unsigned short* pw = pkW + ((size_t)(nt * 4) * 64 + lane) * 8;
    const unsigned short* pr = pkR + ((size_t)(nt * 4) * 64 + lane) * 8;
#pragma unroll
    for (int kc = 0; kc < 4; ++kc) {
      bf16x8 bW = *(const bf16x8*)(pw + (size_t)kc * 64 * 8);
      acc[nt] = __builtin_amdgcn_mfma_f32_16x16x32_bf16(a[kc], bW, acc[nt], 0, 0, 0);
    }
#pragma unroll
    for (int kc = 0; kc < 4; ++kc) {
      bf16x8 bR = *(const bf16x8*)(pr + (size_t)kc * 64 * 8);
      acc[8 + nt] = __builtin_amdgcn_mfma_f32_16x16x32_bf16(g[kc], bR, acc[8 + nt], 0, 0, 0);
    }
  }

  if constexpr (!LAST) {
#pragma unroll
    for (int nt = 0; nt < 8; ++nt) {
      int col = nt * 16 + m;
      float bias = bv[col];
#pragma unroll
      for (int rg = 0; rg < 4; ++rg) {
        int row = rbase + q * 4 + rg;
        if (row < N_NODES)
          gout[row * DIM + col] = f2bf(fmaxf(acc[nt][rg] + acc[8 + nt][rg] + bias, 0.f));
      }
    }
  } else {
    __shared__ float sp[64][132];
    __shared__ int gb[64];
    if (tid < 64) gb[tid] = batch[min(rbase0 + tid, N_NODES - 1)];
#pragma unroll
    for (int nt = 0; nt < 8; ++nt) {
      int col = nt * 16 + m;
      float bias = bv[col];
#pragma unroll
      for (int rg = 0; rg < 4; ++rg) {
        int r   = wave * 16 + q * 4 + rg;
        int row = rbase0 + r;
        float v = fmaxf(acc[nt][rg] + acc[8 + nt][rg] + bias, 0.f);
        if (row < N_NODES) dlast[row * DIM + col] = v;
        sp[r][col] = (row < N_NODES) ? v : 0.f;
      }
    }
    __syncthreads();
    if (tid < DIM) {
      int gprev = gb[0];
      float acc2 = 0.f;
      for (int rr = 0; rr < 64; ++rr) {
        int gg = gb[rr];
        if (gg != gprev) { atomicAdd(&psum[gprev * DIM + tid], acc2); acc2 = 0.f; gprev = gg; }
        acc2 += sp[rr][tid];
      }
      atomicAdd(&psum[gprev * DIM + tid], acc2);
    }
  }
}

// ---------------- MLP head (pool normalization folded into mlp1) --------------

__global__ __launch_bounds__(128) void k_mlp1(const float* __restrict__ psum,
                                              const int* __restrict__ batch,
                                              const float* __restrict__ w,
                                              const float* __restrict__ bias,
                                              float* __restrict__ g1) {
  int g = blockIdx.x, t = threadIdx.x;
  __shared__ int sb[2];
  if (t < 2) {
    int target = g + t;                 // lower_bound(batch, target)
    int lo = 0, hi = N_NODES;
    while (lo < hi) {
      int mid = (lo + hi) >> 1;
      if (batch[mid] < target) lo = mid + 1; else hi = mid;
    }
    sb[t] = lo;
  }
  __syncthreads();
  float cnt = fmaxf((float)(sb[1] - sb[0]), 1.f);
  __shared__ float sp[DIM];
  sp[t] = psum[g * DIM + t] / cnt;
  __syncthreads();
  float acc = bias[t];
#pragma unroll 4
  for (int k = 0; k < DIM; ++k) acc = fmaf(sp[k], w[k * DIM + t], acc);
  g1[g * DIM + t] = fmaxf(acc, 0.f);
}

__global__ __launch_bounds__(128) void k_mlp2(const float* __restrict__ g1,
                                              const float* __restrict__ w,
                                              const float* __restrict__ bias,
                                              float* __restrict__ out) {
  int g = threadIdx.x;   // one thread per graph
  float l[N_CLASSES];
#pragma unroll
  for (int c = 0; c < N_CLASSES; ++c) l[c] = bias[c];
  for (int k = 0; k < DIM; ++k) {
    float gv = g1[g * DIM + k];
#pragma unroll
    for (int c = 0; c < N_CLASSES; ++c) l[c] = fmaf(gv, w[k * N_CLASSES + c], l[c]);
  }
  float m = l[0];
#pragma unroll
  for (int c = 1; c < N_CLASSES; ++c) m = fmaxf(m, l[c]);
  float s = 0.f;
#pragma unroll
  for (int c = 0; c < N_CLASSES; ++c) s += expf(l[c] - m);
  float lse = logf(s) + m;
#pragma unroll
  for (int c = 0; c < N_CLASSES; ++c) out[g * N_CLASSES + c] = l[c] - lse;
}

// ---------------- launch ----------------

extern "C" void kernel_launch(void* const* d_in, const int* in_sizes, int n_in,
                              void* d_out, int out_size, void* d_ws, size_t ws_size,
                              hipStream_t stream) {
  const float* x     = (const float*)d_in[0];
  const int* ei      = (const int*)d_in[1];     // int32 on device (harness)
  const int* batch   = (const int*)d_in[2];     // int32 on device (harness)
  const float* W1  = (const float*)d_in[3];
  const float* R1  = (const float*)d_in[4];
  const float* b1  = (const float*)d_in[5];
  const float* Wc  = (const float*)d_in[6];
  const float* Rc  = (const float*)d_in[7];
  const float* bc  = (const float*)d_in[8];
  const float* l1w = (const float*)d_in[9];
  const float* l1b = (const float*)d_in[10];
  const float* l2w = (const float*)d_in[11];
  const float* l2b = (const float*)d_in[12];

  float* out   = (float*)d_out;
  float* dlast = out + N_GRAPHS * N_CLASSES;   // 'last' region (fp32 layer-4 out)

  // workspace layout (float-word offsets), ~46 MB total (same as R5/R6):
  //   0         X     (3,203,072 w : bf16 50048x128)  -- xb, then g2
  //   3203072   Y     (3,203,072 w)                   -- g1, then g3
  //   6406144   S     (3,203,072 w)                   -- a (agg result, per layer)
  //   9609216   deg   (50,000)   -- zero region start
  //   9659216   cnt   (50,000)
  //   9709216   epk   (1,600,000 w = 800,000 int2; pad-8 needs ~775k, fits)
  //   11309216  dinv  (50,000)
  //   11359216  rowp  (50,016)
  //   11409232  psum  (16,384)   -- zeroed by k_prep psum blocks
  //   11425616  g1    (16,384)
  //   11442000  pk    (65,536 w)
  //   11507536  bsum  (256)
  //   11507792  boff  (256)
  float* ws = (float*)d_ws;
  unsigned short* X = (unsigned short*)ws;
  unsigned short* Y = (unsigned short*)(ws + 3203072);
  unsigned short* S = (unsigned short*)(ws + 6406144);
  int*   deg   = (int*)(ws + 9609216);
  int*   cnt   = (int*)(ws + 9659216);
  int2*  epk   = (int2*)(ws + 9709216);
  float* dinv  = ws + 11309216;
  int*   rowp  = (int*)(ws + 11359216);
  float* psum  = ws + 11409232;
  float* g1    = ws + 11425616;
  unsigned short* pk = (unsigned short*)(ws + 11442000);
  int*   bsum  = (int*)(ws + 11507536);
  int*   boff  = (int*)(ws + 11507792);

  // CSR build (runs every launch; ws is re-poisoned by the harness)
  k_prep<<<NZB4 + NPB + 64, 256, 0, stream>>>((float4*)(ws + 9609216),
                                              (float4*)psum, W1, R1, Wc, Rc, pk);
  k_deg <<<(N_EDGES + 255) / 256, 256, 0, stream>>>(ei, deg);
  k_dinvsum<<<NB_SCAN, 256, 0, stream>>>(deg, dinv, bsum);
  k_bscan<<<1, 256, 0, stream>>>(bsum, boff, rowp);
  k_rowp<<<NB_SCAN, 256, 0, stream>>>(deg, boff, rowp);
  k_fill<<<(N_EDGES + 255) / 256, 256, 0, stream>>>(ei, rowp, cnt, dinv, epk);
  k_rsort<<<NB_SCAN, 256, 0, stream>>>(rowp, deg, epk);   // R7: sorted gather walk

  const int NGB = (N_NODES + 63) / 64;    // 782
  const int NAB = (N_NODES + 7) / 8;      // 6250 (exact: 6250*8 == 50000)

  // xb = bf16(x)
  k_xcast<<<3125, 256, 0, stream>>>(x, X);
  // layer 1: a=agg(xb) -> S ; g1 = relu(a@W1 + xb@R1 + b1) -> Y
  k_gath <<<NAB, 256, 0, stream>>>(X, rowp, epk, S);
  k_gemmc<false><<<NGB, 256, 0, stream>>>(S, X, pk + 0 * 16384, pk + 4 * 16384,
                                          b1, Y, nullptr, nullptr, nullptr);
  // layer 2: a=agg(g1) -> S ; g2 = relu(a@Wc0 + g1@Rc0 + bc0) -> X
  k_gath <<<NAB, 256, 0, stream>>>(Y, rowp, epk, S);
  k_gemmc<false><<<NGB, 256, 0, stream>>>(S, Y, pk + 1 * 16384, pk + 5 * 16384,
                                          bc + 0 * DIM, X, nullptr, nullptr, nullptr);
  // layer 3: a=agg(g2) -> S ; g3 = relu(a@Wc1 + g2@Rc1 + bc1) -> Y
  k_gath <<<NAB, 256, 0, stream>>>(X, rowp, epk, S);
  k_gemmc<false><<<NGB, 256, 0, stream>>>(S, X, pk + 2 * 16384, pk + 6 * 16384,
                                          bc + 1 * DIM, Y, nullptr, nullptr, nullptr);
  // layer 4: a=agg(g3) -> S ; dlast = relu(a@Wc2 + g3@Rc2 + bc2) fp32 + fused pool
  k_gath <<<NAB, 256, 0, stream>>>(Y, rowp, epk, S);
  k_gemmc<true><<<NGB, 256, 0, stream>>>(S, Y, pk + 3 * 16384, pk + 7 * 16384,
                                         bc + 2 * DIM, nullptr, dlast, batch, psum);

  k_mlp1<<<N_GRAPHS, 128, 0, stream>>>(psum, batch, l1w, l1b, g1);
  k_mlp2<<<1, N_GRAPHS, 0, stream>>>(g1, l2w, l2b, out);
}

// Round 8
// 367.382 us; speedup vs baseline: 1.2244x; 1.2244x over previous
//
#include <hip/hip_runtime.h>

#define N_NODES  50000
#define N_EDGES  600000
#define DIM      128
#define N_GRAPHS 128
#define N_CLASSES 10
#define NB_SCAN  196          // ceil(50000/256)
#define ZWORDS   1700000      // zero region: deg+cnt+epk (words)
#define NZB4     1661         // ceil(ZWORDS/4/256)
#define NPB      16           // psum zero blocks: 16384 words /4 /256

// NOTE: harness delivers ALL integer inputs as int32 (const int*).

typedef __bf16 bf16x8 __attribute__((ext_vector_type(8)));
typedef float  f32x4  __attribute__((ext_vector_type(4)));

__device__ inline unsigned short f2bf(float f) {      // RNE float->bf16
  union { float f; unsigned int i; } u; u.f = f;
  unsigned int r = u.i + 0x7fff + ((u.i >> 16) & 1);
  return (unsigned short)(r >> 16);
}
__device__ inline float bf2f(unsigned short s) {
  union { unsigned int i; float f; } u; u.i = ((unsigned int)s) << 16;
  return u.f;
}
__device__ inline bf16x8 pack8(float4 lo, float4 hi) {
  union { bf16x8 v; unsigned short s[8]; } u;
  u.s[0] = f2bf(lo.x); u.s[1] = f2bf(lo.y); u.s[2] = f2bf(lo.z); u.s[3] = f2bf(lo.w);
  u.s[4] = f2bf(hi.x); u.s[5] = f2bf(hi.y); u.s[6] = f2bf(hi.z); u.s[7] = f2bf(hi.w);
  return u.v;
}
__device__ inline bf16x8 zero8() {
  union { bf16x8 v; unsigned short s[8]; } u;
#pragma unroll
  for (int j = 0; j < 8; ++j) u.s[j] = 0;
  return u.v;
}

// ---------------- prep: zero CSR scratch + psum (float4) + pack weights -------

__global__ __launch_bounds__(256) void k_prep(float4* __restrict__ z4,
                                              float4* __restrict__ pz,
                                              const float* __restrict__ W1,
                                              const float* __restrict__ R1,
                                              const float* __restrict__ Wc,
                                              const float* __restrict__ Rc,
                                              unsigned short* __restrict__ pk) {
  if (blockIdx.x < NZB4) {
    int i = blockIdx.x * 256 + threadIdx.x;
    if (i < ZWORDS / 4) z4[i] = make_float4(0.f, 0.f, 0.f, 0.f);
    return;
  }
  if (blockIdx.x < NZB4 + NPB) {        // zero psum: 16*256 = 4096 float4 exact
    int i = (blockIdx.x - NZB4) * 256 + threadIdx.x;
    pz[i] = make_float4(0.f, 0.f, 0.f, 0.f);
    return;
  }
  int pb = blockIdx.x - NZB4 - NPB;     // 0..63
  int mm = pb >> 3, sub = pb & 7;
  const float* src = (mm == 0) ? W1
                   : (mm < 4)  ? Wc + (size_t)(mm - 1) * DIM * DIM
                   : (mm == 4) ? R1
                               : Rc + (size_t)(mm - 5) * DIM * DIM;
  int idx = sub * 256 + threadIdx.x;    // 0..2047 fragment-lane slots
  int lane = idx & 63;
  int kc   = (idx >> 6) & 3;
  int nt   = idx >> 8;
  int col  = nt * 16 + (lane & 15);
  int k0   = kc * 32 + (lane >> 4) * 8;
  unsigned short* dst = pk + (size_t)mm * 16384 + (size_t)idx * 8;
  ushort4 u;
  u.x = f2bf(src[(k0 + 0) * DIM + col]);
  u.y = f2bf(src[(k0 + 1) * DIM + col]);
  u.z = f2bf(src[(k0 + 2) * DIM + col]);
  u.w = f2bf(src[(k0 + 3) * DIM + col]);
  *(ushort4*)&dst[0] = u;
  u.x = f2bf(src[(k0 + 4) * DIM + col]);
  u.y = f2bf(src[(k0 + 5) * DIM + col]);
  u.z = f2bf(src[(k0 + 6) * DIM + col]);
  u.w = f2bf(src[(k0 + 7) * DIM + col]);
  *(ushort4*)&dst[4] = u;
}

// ---------------- CSR build (padded x8; packed int2{src, w_bits}) -------------
// Pad slots stay {0, 0.0f}: gathers hit row 0 (hot), weight 0 -> contribute 0.
// Byte-identical to the R5-proven build. (R7's k_rsort removed: the sort cost
// 89us and bought only ~3us/gather -- random line service is insensitive to
// locality banding.)

__global__ __launch_bounds__(256) void k_deg(const int* __restrict__ ei,
                                             int* __restrict__ deg) {
  int e = blockIdx.x * 256 + threadIdx.x;
  if (e < N_EDGES) atomicAdd(&deg[ei[N_EDGES + e]], 1);
}

__global__ __launch_bounds__(256) void k_dinvsum(const int* __restrict__ deg,
                                                 float* __restrict__ dinv,
                                                 int* __restrict__ bsum) {
  int i = blockIdx.x * 256 + threadIdx.x;
  int t = threadIdx.x;
  int d = (i < N_NODES) ? deg[i] : 0;
  if (i < N_NODES) dinv[i] = (d > 0) ? rsqrtf((float)d) : 0.f;
  int dp = (d + 7) & ~7;
  __shared__ int tmp[256];
  tmp[t] = dp;
  __syncthreads();
  for (int off = 128; off > 0; off >>= 1) {
    if (t < off) tmp[t] += tmp[t + off];
    __syncthreads();
  }
  if (t == 0) bsum[blockIdx.x] = tmp[0];
}

__global__ __launch_bounds__(256) void k_bscan(const int* __restrict__ bsum,
                                               int* __restrict__ boff,
                                               int* __restrict__ rowp) {
  int t = threadIdx.x;
  int v = (t < NB_SCAN) ? bsum[t] : 0;
  __shared__ int tmp[256];
  tmp[t] = v;
  __syncthreads();
  for (int off = 1; off < 256; off <<= 1) {
    int add = (t >= off) ? tmp[t - off] : 0;
    __syncthreads();
    tmp[t] += add;
    __syncthreads();
  }
  boff[t] = tmp[t] - v;          // exclusive
  if (t == 255) rowp[N_NODES] = tmp[255];   // total padded edge count
}

__global__ __launch_bounds__(256) void k_rowp(const int* __restrict__ deg,
                                              const int* __restrict__ boff,
                                              int* __restrict__ rowp) {
  int i = blockIdx.x * 256 + threadIdx.x;
  int t = threadIdx.x;
  int dp = (i < N_NODES) ? ((deg[i] + 7) & ~7) : 0;
  __shared__ int tmp[256];
  tmp[t] = dp;
  __syncthreads();
  for (int off = 1; off < 256; off <<= 1) {
    int add = (t >= off) ? tmp[t - off] : 0;
    __syncthreads();
    tmp[t] += add;
    __syncthreads();
  }
  if (i < N_NODES) rowp[i] = boff[blockIdx.x] + tmp[t] - dp;  // exclusive
}

__global__ __launch_bounds__(256) void k_fill(const int* __restrict__ ei,
                                              const int* __restrict__ rowp,
                                              int* __restrict__ cnt,
                                              const float* __restrict__ dinv,
                                              int2* __restrict__ epk) {
  int e = blockIdx.x * 256 + threadIdx.x;
  if (e < N_EDGES) {
    int s = ei[e];
    int d = ei[N_EDGES + e];
    int p = rowp[d] + atomicAdd(&cnt[d], 1);
    epk[p] = make_int2(s, __float_as_int(dinv[s] * dinv[d]));  // one 8B store
  }
}

// ---------------- x -> bf16 cast (once): xb = bf16(x) -------------------------
// COMMUTATION (R6): agg is row-linear, so agg(g@W) == agg(g)@W. We gather the
// ACTIVATION g itself and fold both matmuls + skip into one GEMM:
//   g_{l} = relu(agg(g_{l-1})@W_l + g_{l-1}@R_l + b_l)

__global__ __launch_bounds__(256) void k_xcast(const float* __restrict__ xf,
                                               unsigned short* __restrict__ xb) {
  int i = blockIdx.x * 256 + threadIdx.x;     // 800,000 chunks of 8, exact grid
  float4 lo = *(const float4*)&xf[i * 8];
  float4 hi = *(const float4*)&xf[i * 8 + 4];
  bf16x8 v = pack8(lo, hi);
  *(bf16x8*)&xb[i * 8] = v;
}

// ---------------- standalone gather: a = agg(gin)  (no skip, no relu) ---------
// R2/R3/R5-proven structure: half-wave per row, pad-8 dual-chain, ushort4.
// Evidence ledger (final): occupancy saturated (R2), extra MLP null (R3),
// streaming removal null (R6), nt hints negative (R4), sorted walk +10% at
// -89us cost (R7). The random row-gather line-service rate is the ceiling.

__global__ __launch_bounds__(256) void k_gath(const unsigned short* __restrict__ hin,
                                              const int* __restrict__ rowp,
                                              const int2* __restrict__ epk,
                                              unsigned short* __restrict__ aout) {
  int n = blockIdx.x * 8 + (threadIdx.x >> 5);
  if (n >= N_NODES) return;
  int l4 = (threadIdx.x & 31) * 4;
  int e0 = rowp[n], e1 = rowp[n + 1];
  float4 accA = make_float4(0.f, 0.f, 0.f, 0.f);
  float4 accB = make_float4(0.f, 0.f, 0.f, 0.f);
  for (int ea = e0, eb = e1 - 4; ea < eb; ea += 4, eb -= 4) {
    int4 p0 = *(const int4*)&epk[ea];
    int4 p1 = *(const int4*)&epk[ea + 2];
    int4 p2 = *(const int4*)&epk[eb];
    int4 p3 = *(const int4*)&epk[eb + 2];
    ushort4 u0 = *(const ushort4*)&hin[p0.x * DIM + l4];
    ushort4 u1 = *(const ushort4*)&hin[p0.z * DIM + l4];
    ushort4 u2 = *(const ushort4*)&hin[p1.x * DIM + l4];
    ushort4 u3 = *(const ushort4*)&hin[p1.z * DIM + l4];
    ushort4 u4 = *(const ushort4*)&hin[p2.x * DIM + l4];
    ushort4 u5 = *(const ushort4*)&hin[p2.z * DIM + l4];
    ushort4 u6 = *(const ushort4*)&hin[p3.x * DIM + l4];
    ushort4 u7 = *(const ushort4*)&hin[p3.z * DIM + l4];
    float w0 = __int_as_float(p0.y), w1 = __int_as_float(p0.w);
    float w2 = __int_as_float(p1.y), w3 = __int_as_float(p1.w);
    float w4 = __int_as_float(p2.y), w5 = __int_as_float(p2.w);
    float w6 = __int_as_float(p3.y), w7 = __int_as_float(p3.w);
    accA.x = fmaf(w0, bf2f(u0.x), fmaf(w1, bf2f(u1.x), fmaf(w2, bf2f(u2.x), fmaf(w3, bf2f(u3.x), accA.x))));
    accA.y = fmaf(w0, bf2f(u0.y), fmaf(w1, bf2f(u1.y), fmaf(w2, bf2f(u2.y), fmaf(w3, bf2f(u3.y), accA.y))));
    accA.z = fmaf(w0, bf2f(u0.z), fmaf(w1, bf2f(u1.z), fmaf(w2, bf2f(u2.z), fmaf(w3, bf2f(u3.z), accA.z))));
    accA.w = fmaf(w0, bf2f(u0.w), fmaf(w1, bf2f(u1.w), fmaf(w2, bf2f(u2.w), fmaf(w3, bf2f(u3.w), accA.w))));
    accB.x = fmaf(w4, bf2f(u4.x), fmaf(w5, bf2f(u5.x), fmaf(w6, bf2f(u6.x), fmaf(w7, bf2f(u7.x), accB.x))));
    accB.y = fmaf(w4, bf2f(u4.y), fmaf(w5, bf2f(u5.y), fmaf(w6, bf2f(u6.y), fmaf(w7, bf2f(u7.y), accB.y))));
    accB.z = fmaf(w4, bf2f(u4.z), fmaf(w5, bf2f(u5.z), fmaf(w6, bf2f(u6.z), fmaf(w7, bf2f(u7.z), accB.z))));
    accB.w = fmaf(w4, bf2f(u4.w), fmaf(w5, bf2f(u5.w), fmaf(w6, bf2f(u6.w), fmaf(w7, bf2f(u7.w), accB.w))));
  }
  ushort4 o;
  o.x = f2bf(accA.x + accB.x);
  o.y = f2bf(accA.y + accB.y);
  o.z = f2bf(accA.z + accB.z);
  o.w = f2bf(accA.w + accB.w);
  *(ushort4*)&aout[n * DIM + l4] = o;
}

// ---------------- dual-A MFMA GEMM: o = relu(a@W + g@R + b) -------------------
// Same HW-verified fragment layout as all previous GEMMs. Non-LAST: bf16 g_l
// (scalar epilogue, R5-proven). LAST: fp32 dlast + FUSED mean-pool (R5-proven
// segment-reduce idiom, extended to the block's 64 rows).

template<bool LAST>
__global__ __launch_bounds__(256) void k_gemmc(const unsigned short* __restrict__ aA,
                                               const unsigned short* __restrict__ gA,
                                               const unsigned short* __restrict__ pkW,
                                               const unsigned short* __restrict__ pkR,
                                               const float* __restrict__ bv,
                                               unsigned short* __restrict__ gout,
                                               float* __restrict__ dlast,
                                               const int* __restrict__ batch,
                                               float* __restrict__ psum) {
  const int tid  = threadIdx.x;
  const int wave = tid >> 6, lane = tid & 63;
  const int m = lane & 15, q = lane >> 4;
  const int rbase0 = blockIdx.x * 64;
  const int rbase  = rbase0 + wave * 16;
  const int arow   = rbase + m;
  const bool aok   = arow < N_NODES;

  bf16x8 a[4], g[4];
#pragma unroll
  for (int kc = 0; kc < 4; ++kc) {
    a[kc] = aok ? *(const bf16x8*)&aA[arow * DIM + kc * 32 + q * 8] : zero8();
    g[kc] = aok ? *(const bf16x8*)&gA[arow * DIM + kc * 32 + q * 8] : zero8();
  }

  f32x4 acc[16];
#pragma unroll
  for (int t = 0; t < 16; ++t) acc[t] = (f32x4){0.f, 0.f, 0.f, 0.f};

#pragma unroll
  for (int nt = 0; nt < 8; ++nt) {
    const unsigned short* pw = pkW + ((size_t)(nt * 4) * 64 + lane) * 8;
    const unsigned short* pr = pkR + ((size_t)(nt * 4) * 64 + lane) * 8;
#pragma unroll
    for (int kc = 0; kc < 4; ++kc) {
      bf16x8 bW = *(const bf16x8*)(pw + (size_t)kc * 64 * 8);
      acc[nt] = __builtin_amdgcn_mfma_f32_16x16x32_bf16(a[kc], bW, acc[nt], 0, 0, 0);
    }
#pragma unroll
    for (int kc = 0; kc < 4; ++kc) {
      bf16x8 bR = *(const bf16x8*)(pr + (size_t)kc * 64 * 8);
      acc[8 + nt] = __builtin_amdgcn_mfma_f32_16x16x32_bf16(g[kc], bR, acc[8 + nt], 0, 0, 0);
    }
  }

  if constexpr (!LAST) {
#pragma unroll
    for (int nt = 0; nt < 8; ++nt) {
      int col = nt * 16 + m;
      float bias = bv[col];
#pragma unroll
      for (int rg = 0; rg < 4; ++rg) {
        int row = rbase + q * 4 + rg;
        if (row < N_NODES)
          gout[row * DIM + col] = f2bf(fmaxf(acc[nt][rg] + acc[8 + nt][rg] + bias, 0.f));
      }
    }
  } else {
    __shared__ float sp[64][132];
    __shared__ int gb[64];
    if (tid < 64) gb[tid] = batch[min(rbase0 + tid, N_NODES - 1)];
#pragma unroll
    for (int nt = 0; nt < 8; ++nt) {
      int col = nt * 16 + m;
      float bias = bv[col];
#pragma unroll
      for (int rg = 0; rg < 4; ++rg) {
        int r   = wave * 16 + q * 4 + rg;
        int row = rbase0 + r;
        float v = fmaxf(acc[nt][rg] + acc[8 + nt][rg] + bias, 0.f);
        if (row < N_NODES) dlast[row * DIM + col] = v;
        sp[r][col] = (row < N_NODES) ? v : 0.f;
      }
    }
    __syncthreads();
    if (tid < DIM) {
      int gprev = gb[0];
      float acc2 = 0.f;
      for (int rr = 0; rr < 64; ++rr) {
        int gg = gb[rr];
        if (gg != gprev) { atomicAdd(&psum[gprev * DIM + tid], acc2); acc2 = 0.f; gprev = gg; }
        acc2 += sp[rr][tid];
      }
      atomicAdd(&psum[gprev * DIM + tid], acc2);
    }
  }
}

// ---------------- MLP head (pool normalization folded into mlp1) --------------

__global__ __launch_bounds__(128) void k_mlp1(const float* __restrict__ psum,
                                              const int* __restrict__ batch,
                                              const float* __restrict__ w,
                                              const float* __restrict__ bias,
                                              float* __restrict__ g1) {
  int g = blockIdx.x, t = threadIdx.x;
  __shared__ int sb[2];
  if (t < 2) {
    int target = g + t;                 // lower_bound(batch, target)
    int lo = 0, hi = N_NODES;
    while (lo < hi) {
      int mid = (lo + hi) >> 1;
      if (batch[mid] < target) lo = mid + 1; else hi = mid;
    }
    sb[t] = lo;
  }
  __syncthreads();
  float cnt = fmaxf((float)(sb[1] - sb[0]), 1.f);
  __shared__ float sp[DIM];
  sp[t] = psum[g * DIM + t] / cnt;
  __syncthreads();
  float acc = bias[t];
#pragma unroll 4
  for (int k = 0; k < DIM; ++k) acc = fmaf(sp[k], w[k * DIM + t], acc);
  g1[g * DIM + t] = fmaxf(acc, 0.f);
}

__global__ __launch_bounds__(128) void k_mlp2(const float* __restrict__ g1,
                                              const float* __restrict__ w,
                                              const float* __restrict__ bias,
                                              float* __restrict__ out) {
  int g = threadIdx.x;   // one thread per graph
  float l[N_CLASSES];
#pragma unroll
  for (int c = 0; c < N_CLASSES; ++c) l[c] = bias[c];
  for (int k = 0; k < DIM; ++k) {
    float gv = g1[g * DIM + k];
#pragma unroll
    for (int c = 0; c < N_CLASSES; ++c) l[c] = fmaf(gv, w[k * N_CLASSES + c], l[c]);
  }
  float m = l[0];
#pragma unroll
  for (int c = 1; c < N_CLASSES; ++c) m = fmaxf(m, l[c]);
  float s = 0.f;
#pragma unroll
  for (int c = 0; c < N_CLASSES; ++c) s += expf(l[c] - m);
  float lse = logf(s) + m;
#pragma unroll
  for (int c = 0; c < N_CLASSES; ++c) out[g * N_CLASSES + c] = l[c] - lse;
}

// ---------------- launch ----------------

extern "C" void kernel_launch(void* const* d_in, const int* in_sizes, int n_in,
                              void* d_out, int out_size, void* d_ws, size_t ws_size,
                              hipStream_t stream) {
  const float* x     = (const float*)d_in[0];
  const int* ei      = (const int*)d_in[1];     // int32 on device (harness)
  const int* batch   = (const int*)d_in[2];     // int32 on device (harness)
  const float* W1  = (const float*)d_in[3];
  const float* R1  = (const float*)d_in[4];
  const float* b1  = (const float*)d_in[5];
  const float* Wc  = (const float*)d_in[6];
  const float* Rc  = (const float*)d_in[7];
  const float* bc  = (const float*)d_in[8];
  const float* l1w = (const float*)d_in[9];
  const float* l1b = (const float*)d_in[10];
  const float* l2w = (const float*)d_in[11];
  const float* l2b = (const float*)d_in[12];

  float* out   = (float*)d_out;
  float* dlast = out + N_GRAPHS * N_CLASSES;   // 'last' region (fp32 layer-4 out)

  // workspace layout (float-word offsets), ~46 MB total (same as R5/R6):
  //   0         X     (3,203,072 w : bf16 50048x128)  -- xb, then g2
  //   3203072   Y     (3,203,072 w)                   -- g1, then g3
  //   6406144   S     (3,203,072 w)                   -- a (agg result, per layer)
  //   9609216   deg   (50,000)   -- zero region start
  //   9659216   cnt   (50,000)
  //   9709216   epk   (1,600,000 w = 800,000 int2; pad-8 needs ~775k, fits)
  //   11309216  dinv  (50,000)
  //   11359216  rowp  (50,016)
  //   11409232  psum  (16,384)   -- zeroed by k_prep psum blocks
  //   11425616  g1    (16,384)
  //   11442000  pk    (65,536 w)
  //   11507536  bsum  (256)
  //   11507792  boff  (256)
  float* ws = (float*)d_ws;
  unsigned short* X = (unsigned short*)ws;
  unsigned short* Y = (unsigned short*)(ws + 3203072);
  unsigned short* S = (unsigned short*)(ws + 6406144);
  int*   deg   = (int*)(ws + 9609216);
  int*   cnt   = (int*)(ws + 9659216);
  int2*  epk   = (int2*)(ws + 9709216);
  float* dinv  = ws + 11309216;
  int*   rowp  = (int*)(ws + 11359216);
  float* psum  = ws + 11409232;
  float* g1    = ws + 11425616;
  unsigned short* pk = (unsigned short*)(ws + 11442000);
  int*   bsum  = (int*)(ws + 11507536);
  int*   boff  = (int*)(ws + 11507792);

  // CSR build (runs every launch; ws is re-poisoned by the harness)
  k_prep<<<NZB4 + NPB + 64, 256, 0, stream>>>((float4*)(ws + 9609216),
                                              (float4*)psum, W1, R1, Wc, Rc, pk);
  k_deg <<<(N_EDGES + 255) / 256, 256, 0, stream>>>(ei, deg);
  k_dinvsum<<<NB_SCAN, 256, 0, stream>>>(deg, dinv, bsum);
  k_bscan<<<1, 256, 0, stream>>>(bsum, boff, rowp);
  k_rowp<<<NB_SCAN, 256, 0, stream>>>(deg, boff, rowp);
  k_fill<<<(N_EDGES + 255) / 256, 256, 0, stream>>>(ei, rowp, cnt, dinv, epk);

  const int NGB = (N_NODES + 63) / 64;    // 782
  const int NAB = (N_NODES + 7) / 8;      // 6250 (exact: 6250*8 == 50000)

  // xb = bf16(x)
  k_xcast<<<3125, 256, 0, stream>>>(x, X);
  // layer 1: a=agg(xb) -> S ; g1 = relu(a@W1 + xb@R1 + b1) -> Y
  k_gath <<<NAB, 256, 0, stream>>>(X, rowp, epk, S);
  k_gemmc<false><<<NGB, 256, 0, stream>>>(S, X, pk + 0 * 16384, pk + 4 * 16384,
                                          b1, Y, nullptr, nullptr, nullptr);
  // layer 2: a=agg(g1) -> S ; g2 = relu(a@Wc0 + g1@Rc0 + bc0) -> X
  k_gath <<<NAB, 256, 0, stream>>>(Y, rowp, epk, S);
  k_gemmc<false><<<NGB, 256, 0, stream>>>(S, Y, pk + 1 * 16384, pk + 5 * 16384,
                                          bc + 0 * DIM, X, nullptr, nullptr, nullptr);
  // layer 3: a=agg(g2) -> S ; g3 = relu(a@Wc1 + g2@Rc1 + bc1) -> Y
  k_gath <<<NAB, 256, 0, stream>>>(X, rowp, epk, S);
  k_gemmc<false><<<NGB, 256, 0, stream>>>(S, X, pk + 2 * 16384, pk + 6 * 16384,
                                          bc + 1 * DIM, Y, nullptr, nullptr, nullptr);
  // layer 4: a=agg(g3) -> S ; dlast = relu(a@Wc2 + g3@Rc2 + bc2) fp32 + fused pool
  k_gath <<<NAB, 256, 0, stream>>>(Y, rowp, epk, S);
  k_gemmc<true><<<NGB, 256, 0, stream>>>(S, Y, pk + 3 * 16384, pk + 7 * 16384,
                                         bc + 2 * DIM, nullptr, dlast, batch, psum);

  k_mlp1<<<N_GRAPHS, 128, 0, stream>>>(psum, batch, l1w, l1b, g1);
  k_mlp2<<<1, N_GRAPHS, 0, stream>>>(g1, l2w, l2b, out);
}